// Round 10
// baseline (1352.565 us; speedup 1.0000x reference)
//
#include <hip/hip_runtime.h>
#include <hip/hip_bf16.h>

typedef __attribute__((ext_vector_type(8))) short short8;
typedef __attribute__((ext_vector_type(4))) float f32x4;

static __device__ __forceinline__ float b2f(unsigned short u) {
  return __uint_as_float(((unsigned int)u) << 16);
}
static __device__ __forceinline__ unsigned short f2bs(float f) {
  unsigned int u = __float_as_uint(f);
  u = u + 0x7FFFu + ((u >> 16) & 1u);   // RNE (no NaN inputs here)
  return (unsigned short)(u >> 16);
}
// pair f32 -> packed bf16 (HW v_cvt_pk_bf16_f32, RNE)
static __device__ __forceinline__ unsigned int cvt2(float a, float b) {
  __hip_bfloat162 h = __float22bfloat162_rn(make_float2(a, b));
  return *(unsigned int*)&h;
}

// async global->LDS DMA, 16B per lane; LDS dest = wave-uniform base + lane*16
static __device__ __forceinline__ void gload16(const void* g, void* l) {
  __builtin_amdgcn_global_load_lds(
      (const __attribute__((address_space(1))) void*)g,
      (__attribute__((address_space(3))) void*)l, 16, 0, 0);
}

enum { EPI_BF16_SUMSQ = 1, EPI_BF16 = 2, EPI_F32_RESID = 3 };

// ---------------- bf16-A GEMM (m97 structure, proven Round 6) ----------------
// rowscale (raw sumsq): EPI_BF16 -> v = (acc*escale)*rs + bias;
//                       EPI_F32_RESID -> v = acc + bias + rs*resid.
template<int BM, int BN, int EPI, bool XCD1D>
__global__ __launch_bounds__(256, 4) void gemm_bt(
    const short* __restrict__ A, const short* __restrict__ B, void* __restrict__ Cv,
    const float* __restrict__ bias, const unsigned short* __restrict__ residb,
    float* __restrict__ sumsq, const float* __restrict__ rowscale,
    long lda, long ldb, long ldc, int K, float escale,
    long aZ, long bZ, long cZ, int biasZ, int ncolb)
{
  constexpr int BK = 64;
  constexpr int WM = BM / 2, WN = BN / 2, MR = WM / 16, NR = WN / 16;
  __shared__ __align__(16) short As[BM * BK];
  __shared__ __align__(16) short Bs[BN * BK];
  const int t = threadIdx.x;
  const int zb = blockIdx.z;
  long bxc, byp;
  if constexpr (XCD1D) {
    int bid = blockIdx.x;
    int per = gridDim.x >> 3;
    int ppx = per / ncolb;
    int xcd = bid & 7, j = bid >> 3;
    byp = (long)xcd * ppx + j / ncolb;
    bxc = j % ncolb;
  } else {
    byp = blockIdx.x; bxc = blockIdx.y;
  }
  const long row0 = byp * BM;
  const long col0 = bxc * BN;
  const int wave = t >> 6, lane = t & 63;
  const int wr = wave >> 1, wc = wave & 1;
  const int lr = lane & 15, lg = lane >> 4;
  const short* Az = A + (size_t)zb * aZ;
  const short* Bz = B + (size_t)zb * bZ;
  const int lrow8 = lane >> 3;
  const int lgran = (lane & 7) ^ lrow8;

  auto dmaA = [&](int k0) {
    #pragma unroll
    for (int i = 0; i < BM / 32; ++i) {
      int c = wave * (BM / 32) + i;
      gload16(Az + (size_t)(row0 + c * 8 + lrow8) * lda + k0 + lgran * 8,
              &As[c * 512]);
    }
  };
  auto dmaB = [&](int k0) {
    #pragma unroll
    for (int i = 0; i < BN / 32; ++i) {
      int c = wave * (BN / 32) + i;
      gload16(Bz + (size_t)(col0 + c * 8 + lrow8) * ldb + k0 + lgran * 8,
              &Bs[c * 512]);
    }
  };

  const f32x4 zero4 = {0.f, 0.f, 0.f, 0.f};
  f32x4 acc[MR][NR];
  #pragma unroll
  for (int m = 0; m < MR; ++m)
    #pragma unroll
    for (int n = 0; n < NR; ++n) acc[m][n] = zero4;

  dmaA(0); dmaB(0);
  __syncthreads();

  const int nk = K / BK;
  for (int kt = 0; kt < nk; ++kt) {
    #pragma unroll
    for (int kk = 0; kk < 2; ++kk) {
      short8 a[MR], b[NR];
      #pragma unroll
      for (int m = 0; m < MR; ++m) {
        int row = wr * WM + m * 16 + lr, col = kk * 32 + lg * 8;
        a[m] = *(const short8*)&As[row * 64 + (col ^ ((row & 7) << 3))];
      }
      #pragma unroll
      for (int n = 0; n < NR; ++n) {
        int row = wc * WN + n * 16 + lr, col = kk * 32 + lg * 8;
        b[n] = *(const short8*)&Bs[row * 64 + (col ^ ((row & 7) << 3))];
      }
      #pragma unroll
      for (int m = 0; m < MR; ++m)
        #pragma unroll
        for (int n = 0; n < NR; ++n)
          acc[m][n] = __builtin_amdgcn_mfma_f32_16x16x32_bf16(a[m], b[n], acc[m][n], 0, 0, 0);
    }
    if (kt + 1 < nk) {
      __syncthreads();
      dmaA((kt + 1) * BK); dmaB((kt + 1) * BK);
      __syncthreads();
    }
  }

  const float* biasz = bias ? (bias + (size_t)zb * biasZ) : nullptr;
  float* Cf = (float*)Cv;
  unsigned short* Cb = (unsigned short*)Cv;
  #pragma unroll
  for (int m = 0; m < MR; ++m) {
    #pragma unroll
    for (int i = 0; i < 4; ++i) {
      long row = row0 + wr * WM + m * 16 + lg * 4 + i;
      float rs = 1.f;
      if (rowscale) rs = 1.f / (sqrtf(rowscale[row]) + 1e-6f);
      float sq = 0.f;
      #pragma unroll
      for (int n = 0; n < NR; ++n) {
        long col = col0 + wc * WN + n * 16 + lr;
        float v = acc[m][n][i] * escale;
        size_t ci = (size_t)zb * cZ + (size_t)row * ldc + col;
        if constexpr (EPI == EPI_F32_RESID) {
          v += biasz[col] + rs * b2f(residb[(size_t)row * ldc + col]);
          Cf[ci] = v;
        } else if constexpr (EPI == EPI_BF16_SUMSQ) {
          if (biasz) v += biasz[col];
          Cb[ci] = f2bs(v);
          sq += v * v;
        } else {                      // EPI_BF16
          v *= rs;
          if (biasz) v += biasz[col];
          Cb[ci] = f2bs(v);
        }
      }
      if constexpr (EPI == EPI_BF16_SUMSQ) {
        #pragma unroll
        for (int off = 1; off < 16; off <<= 1) sq += __shfl_xor(sq, off);
        if (lr == 0) atomicAdd(&sumsq[row], sq);
      }
    }
  }
}

// -------- f32-A fused GEMM v3: C_bf16[M,768] = A_f32[M,K] @ B_bf16[768,K]^T
// + bias, + row sumsq. A loaded DIRECTLY global->registers per wave (no LDS),
// converted with HW cvt_pk; only B goes through LDS (double-buffered 2x16KB,
// ONE barrier per K-step, DMA overlaps compute). Removes the LDS-pipe
// bottleneck (144 -> 48 KB per block-K-step).
template<bool XCD1D>
__global__ __launch_bounds__(256, 3) void gemm_af32(
    const float* __restrict__ A, const short* __restrict__ B,
    unsigned short* __restrict__ C, const float* __restrict__ bias,
    float* __restrict__ sumsq, int K, int ncolb)
{
  constexpr int BM = 128, BN = 128, BK = 64, WM = 64, WN = 64, MR = 4, NR = 4;
  __shared__ __align__(16) short Bs[2][BN * BK];
  const int t = threadIdx.x;
  long bxc, byp;
  if constexpr (XCD1D) {
    int bid = blockIdx.x;
    int per = gridDim.x >> 3;
    int ppx = per / ncolb;
    int xcd = bid & 7, j = bid >> 3;
    byp = (long)xcd * ppx + j / ncolb;
    bxc = j % ncolb;
  } else {
    byp = blockIdx.x; bxc = blockIdx.y;
  }
  const long row0 = byp * BM;
  const long col0 = bxc * BN;
  const int wave = t >> 6, lane = t & 63;
  const int wr = wave >> 1, wc = wave & 1;
  const int lr = lane & 15, lg = lane >> 4;
  const int lrow8 = lane >> 3;
  const int lgran8 = (lane & 7) ^ lrow8;   // B-side swizzle (unchanged)

  // per-lane A row base pointers (rows fixed across K loop)
  const float* ap[MR];
  #pragma unroll
  for (int m = 0; m < MR; ++m)
    ap[m] = A + (size_t)(row0 + wr * WM + m * 16 + lr) * K + lg * 8;

  auto dmaB = [&](int buf, int k0) {
    #pragma unroll
    for (int i = 0; i < 4; ++i) {
      int c = wave * 4 + i;              // 8-row chunk
      gload16(B + (size_t)(col0 + c * 8 + lrow8) * K + k0 + lgran8 * 8,
              &Bs[buf][c * 512]);
    }
  };

  float4 pa[MR][2][2];   // [m][kk][half] : 8 f32 per (m,kk)
  auto loadA = [&](int k0) {
    #pragma unroll
    for (int m = 0; m < MR; ++m) {
      const float* rp = ap[m] + k0;
      pa[m][0][0] = *(const float4*)rp;
      pa[m][0][1] = *(const float4*)(rp + 4);
      pa[m][1][0] = *(const float4*)(rp + 32);
      pa[m][1][1] = *(const float4*)(rp + 36);
    }
  };

  const f32x4 zero4 = {0.f, 0.f, 0.f, 0.f};
  f32x4 acc[MR][NR];
  #pragma unroll
  for (int m = 0; m < MR; ++m)
    #pragma unroll
    for (int n = 0; n < NR; ++n) acc[m][n] = zero4;

  dmaB(0, 0);
  loadA(0);
  __syncthreads();   // drains B DMA (and A loads)

  const int nk = K / BK;
  for (int kt = 0; kt < nk; ++kt) {
    const int cur = kt & 1;
    if (kt + 1 < nk) dmaB(cur ^ 1, (kt + 1) * BK);   // overlaps compute
    #pragma unroll
    for (int kk = 0; kk < 2; ++kk) {
      short8 a[MR], b[NR];
      #pragma unroll
      for (int m = 0; m < MR; ++m) {
        union { short8 s; unsigned int u[4]; } U;
        U.u[0] = cvt2(pa[m][kk][0].x, pa[m][kk][0].y);
        U.u[1] = cvt2(pa[m][kk][0].z, pa[m][kk][0].w);
        U.u[2] = cvt2(pa[m][kk][1].x, pa[m][kk][1].y);
        U.u[3] = cvt2(pa[m][kk][1].z, pa[m][kk][1].w);
        a[m] = U.s;
      }
      #pragma unroll
      for (int n = 0; n < NR; ++n) {
        int row = wc * WN + n * 16 + lr, col = kk * 32 + lg * 8;
        b[n] = *(const short8*)&Bs[cur][row * 64 + (col ^ ((row & 7) << 3))];
      }
      #pragma unroll
      for (int m = 0; m < MR; ++m)
        #pragma unroll
        for (int n = 0; n < NR; ++n)
          acc[m][n] = __builtin_amdgcn_mfma_f32_16x16x32_bf16(a[m], b[n], acc[m][n], 0, 0, 0);
    }
    if (kt + 1 < nk) loadA((kt + 1) * BK);   // pa free after cvt
    __syncthreads();   // next B buffer ready; Bs[cur] free for kt+2
  }

  #pragma unroll
  for (int m = 0; m < MR; ++m) {
    #pragma unroll
    for (int i = 0; i < 4; ++i) {
      long row = row0 + wr * WM + m * 16 + lg * 4 + i;
      float sq = 0.f;
      #pragma unroll
      for (int n = 0; n < NR; ++n) {
        long col = col0 + wc * WN + n * 16 + lr;
        float v = acc[m][n][i] + bias[col];
        C[(size_t)row * 768 + col] = f2bs(v);
        sq += v * v;
      }
      #pragma unroll
      for (int off = 1; off < 16; off <<= 1) sq += __shfl_xor(sq, off);
      if (lr == 0) atomicAdd(&sumsq[row], sq);
    }
  }
}

// all weight conversions in one dispatch
__global__ __launch_bounds__(256) void wconv_kernel(
    const float* __restrict__ Wx, const float* __restrict__ Wy,
    const float* __restrict__ ipw, const float* __restrict__ Wo,
    unsigned short* __restrict__ dWx, unsigned short* __restrict__ dWy,
    unsigned short* __restrict__ dWq, unsigned short* __restrict__ dWkT,
    unsigned short* __restrict__ dWv, unsigned short* __restrict__ dWo)
{
  long i = (long)blockIdx.x * 256 + threadIdx.x;
  if (i < 1179648) { dWx[i] = f2bs(Wx[i]); return; }
  i -= 1179648;
  if (i < 786432) { dWy[i] = f2bs(Wy[i]); return; }
  i -= 786432;
  if (i < 589824) { dWq[i] = f2bs(ipw[i]); return; }
  i -= 589824;
  if (i < 589824) {  // WkT[h][n][j] = Wk[h*64+j][n]
    int h = (int)(i / 49152), r = (int)(i % 49152);
    int nn = r >> 6, j = r & 63;
    dWkT[i] = f2bs(ipw[(size_t)(768 + h * 64 + j) * 768 + nn]);
    return;
  }
  i -= 589824;
  if (i < 589824) { dWv[i] = f2bs(ipw[2 * 589824 + i]); return; }
  i -= 589824;
  if (i < 589824) { dWo[i] = f2bs(Wo[i]); }
}

// Per-token fused: S = (qk . z)*invn -> softmax_w -> a = attn*invn -> u = a @ z
__global__ __launch_bounds__(256) void attn_kernel(
    const unsigned short* __restrict__ z, const unsigned short* __restrict__ qk,
    const float* __restrict__ ssy, unsigned short* __restrict__ u)
{
  __shared__ __align__(16) unsigned short zl[16 * 768];
  __shared__ __align__(16) unsigned short ql[12 * 768];
  __shared__ float sc[3][256];
  __shared__ float al[256];
  __shared__ float il[16];
  const int t = threadIdx.x;
  const long m = blockIdx.x;
  const int wv = t >> 6, lane = t & 63;
  const int lr = lane & 15, lg = lane >> 4;

  for (int s = t; s < 1536; s += 256) {
    int row = s / 96, g = s % 96;
    *(short8*)&zl[row * 768 + ((g ^ (row & 7)) << 3)] =
        *(const short8*)(z + m * 12288 + (size_t)s * 8);
  }
  for (int s = t; s < 1152; s += 256) {
    int row = s / 96, g = s % 96;
    *(short8*)&ql[row * 768 + ((g ^ (row & 7)) << 3)] =
        *(const short8*)(qk + m * 9216 + (size_t)s * 8);
  }
  if (t < 16) il[t] = 1.f / (sqrtf(ssy[m * 16 + t]) + 1e-6f);
  __syncthreads();

  f32x4 c = {0.f, 0.f, 0.f, 0.f};
  #pragma unroll
  for (int i = 0; i < 6; ++i) {
    int gb = wv * 24 + i * 4 + lg;
    short8 a = (lr < 12) ? *(const short8*)&ql[lr * 768 + ((gb ^ (lr & 7)) << 3)]
                         : short8{0, 0, 0, 0, 0, 0, 0, 0};
    short8 b = *(const short8*)&zl[lr * 768 + ((gb ^ (lr & 7)) << 3)];
    c = __builtin_amdgcn_mfma_f32_16x16x32_bf16(a, b, c, 0, 0, 0);
  }
  if (wv > 0) {
    #pragma unroll
    for (int i = 0; i < 4; ++i) sc[wv - 1][(lg * 4 + i) * 16 + lr] = c[i];
  }
  __syncthreads();
  if (wv == 0) {
    #pragma unroll
    for (int i = 0; i < 4; ++i) {
      int idx = (lg * 4 + i) * 16 + lr;
      float s = (c[i] + sc[0][idx] + sc[1][idx] + sc[2][idx]) * il[lr];
      float mx = s;
      #pragma unroll
      for (int off = 1; off < 16; off <<= 1) mx = fmaxf(mx, __shfl_xor(mx, off));
      float e = __expf(s - mx);
      float sum = e;
      #pragma unroll
      for (int off = 1; off < 16; off <<= 1) sum += __shfl_xor(sum, off);
      al[idx] = e / sum * il[lr];
    }
  }
  __syncthreads();

  for (int s = t; s < 1152; s += 256) {
    int h = s / 96, gd = s % 96;
    float acc[8] = {0.f, 0.f, 0.f, 0.f, 0.f, 0.f, 0.f, 0.f};
    #pragma unroll
    for (int w = 0; w < 16; ++w) {
      float aw = al[h * 16 + w];
      short8 zz = *(const short8*)&zl[w * 768 + ((gd ^ (w & 7)) << 3)];
      #pragma unroll
      for (int j = 0; j < 8; ++j) acc[j] += aw * b2f((unsigned short)zz[j]);
    }
    short8 o;
    #pragma unroll
    for (int j = 0; j < 8; ++j) o[j] = (short)f2bs(acc[j]);
    *(short8*)&u[m * 9216 + (size_t)s * 8] = o;
  }
}

__global__ __launch_bounds__(256) void ln_kernel(const float* __restrict__ R,
                                                 const float* __restrict__ w,
                                                 const float* __restrict__ b,
                                                 float* __restrict__ out) {
  const long row = blockIdx.x;
  const int t = threadIdx.x;
  const float* rr = R + row * 768;
  float v0 = rr[t], v1 = rr[t + 256], v2 = rr[t + 512];
  float s = v0 + v1 + v2;
  #pragma unroll
  for (int off = 1; off < 64; off <<= 1) s += __shfl_xor(s, off);
  __shared__ float ps[4];
  __shared__ float ps2[4];
  const int wave = t >> 6, lane = t & 63;
  if (lane == 0) ps[wave] = s;
  __syncthreads();
  const float mean = (ps[0] + ps[1] + ps[2] + ps[3]) * (1.f / 768.f);
  const float d0 = v0 - mean, d1 = v1 - mean, d2 = v2 - mean;
  float q = d0 * d0 + d1 * d1 + d2 * d2;
  #pragma unroll
  for (int off = 1; off < 64; off <<= 1) q += __shfl_xor(q, off);
  if (lane == 0) ps2[wave] = q;
  __syncthreads();
  const float var = (ps2[0] + ps2[1] + ps2[2] + ps2[3]) * (1.f / 768.f);
  const float rs = rsqrtf(var + 1e-6f);
  float* oo = out + row * 768;
  oo[t]       = d0 * rs * w[t]       + b[t];
  oo[t + 256] = d1 * rs * w[t + 256] + b[t + 256];
  oo[t + 512] = d2 * rs * w[t + 512] + b[t + 512];
}

extern "C" void kernel_launch(void* const* d_in, const int* in_sizes, int n_in,
                              void* d_out, int out_size, void* d_ws, size_t ws_size,
                              hipStream_t stream) {
  const float* x   = (const float*)d_in[0];   // (8,1024,1536)
  const float* y   = (const float*)d_in[1];   // (8,16384,1024)
  const float* Wx  = (const float*)d_in[2];   // (768,1536)
  const float* bx  = (const float*)d_in[3];
  const float* Wy  = (const float*)d_in[4];   // (768,1024)
  const float* by  = (const float*)d_in[5];
  const float* ipw = (const float*)d_in[6];   // (2304,768)
  const float* ipb = (const float*)d_in[7];
  const float* Wo  = (const float*)d_in[8];   // (768,768)
  const float* ob  = (const float*)d_in[9];
  const float* lnw = (const float*)d_in[10];
  const float* lnb = (const float*)d_in[11];
  float* out = (float*)d_out;

  char* ws = (char*)d_ws;
  size_t off = 0;
  auto alloc = [&](size_t bytes) {
    void* p = ws + off;
    off += (bytes + 4095) & ~(size_t)4095;
    return p;
  };
  unsigned short* Wx_b  = (unsigned short*)alloc(768L * 1536 * 2);
  unsigned short* Wy_b  = (unsigned short*)alloc(768L * 1024 * 2);
  unsigned short* Wq_b  = (unsigned short*)alloc(768L * 768 * 2);
  unsigned short* WkT_b = (unsigned short*)alloc(768L * 768 * 2);
  unsigned short* Wv_b  = (unsigned short*)alloc(768L * 768 * 2);
  unsigned short* Wo_b  = (unsigned short*)alloc(768L * 768 * 2);
  float* ssx = (float*)alloc(8192L * 4);
  float* ssy = (float*)alloc(131072L * 4);
  unsigned short* z_b  = (unsigned short*)alloc(131072L * 768 * 2);
  unsigned short* xq_b = (unsigned short*)alloc(8192L * 768 * 2);
  char* reg = (char*)alloc(134217728L * 2);    // 256 MB scratch region
  unsigned short* q_b  = (unsigned short*)(reg + 25165824);       // 12.6 MB
  unsigned short* qk_b = (unsigned short*)(reg + 37748736);       // 151 MB (also u)
  unsigned short* o_b  = (unsigned short*)(reg + 188743680);      // 12.6 MB
  float*          r_f  = (float*)(reg + 201326592);               // 25.2 MB
  (void)ws_size; (void)in_sizes; (void)n_in; (void)out_size;

  hipMemsetAsync(ssx, 0, 8192L * 4, stream);
  hipMemsetAsync(ssy, 0, 131072L * 4, stream);

  // all weights -> bf16 in one dispatch (4325376 elems)
  wconv_kernel<<<16896, 256, 0, stream>>>(Wx, Wy, ipw, Wo,
                                          Wx_b, Wy_b, Wq_b, WkT_b, Wv_b, Wo_b);

  // z = y @ Wy^T + by (bf16 + sumsq), A direct-to-reg, XCD-contiguous panels
  gemm_af32<true><<<6144, 256, 0, stream>>>(
      y, (const short*)Wy_b, z_b, by, ssy, 1024, 6);

  // xq_raw = x @ Wx^T + bx (bf16, UNSCALED, + sumsq); scale folded downstream
  gemm_af32<false><<<dim3(64, 6, 1), 256, 0, stream>>>(
      x, (const short*)Wx_b, xq_b, bx, ssx, 1536, 0);

  // q = rs[m]*(xq_raw @ Wq^T) + bq   (rowscale folded into epilogue)
  gemm_bt<128, 128, EPI_BF16, false><<<dim3(64, 6, 1), 256, 0, stream>>>(
      (const short*)xq_b, (const short*)Wq_b, q_b, ipb, nullptr, nullptr, ssx,
      768, 768, 768, 768, 1.f, 0, 0, 0, 0, 0);

  // qk[m,h,:] = scale * q[m,h*64:+64] @ WkT[h]   (bk dropped: softmax-invariant)
  gemm_bt<128, 128, EPI_BF16, false><<<dim3(64, 6, 12), 256, 0, stream>>>(
      (const short*)q_b, (const short*)WkT_b, qk_b, nullptr, nullptr, nullptr, nullptr,
      768, 64, 9216, 64, 0.125f, 64, 49152, 768, 0, 0);

  // fused scores/softmax/u  (u overwrites qk slice per token)
  attn_kernel<<<8192, 256, 0, stream>>>(z_b, qk_b, ssy, qk_b);

  // o[:,h*64:+64] = u[:,h,:] @ Wv_h^T + bv_h
  gemm_bt<128, 64, EPI_BF16, false><<<dim3(64, 1, 12), 256, 0, stream>>>(
      (const short*)qk_b, (const short*)Wv_b, o_b, ipb + 1536, nullptr, nullptr, nullptr,
      9216, 768, 768, 768, 1.f, 768, 49152, 64, 64, 0);

  // r = o @ out_w^T + out_b + rs[m]*xq_raw   (residual row-scale in epilogue)
  gemm_bt<128, 128, EPI_F32_RESID, false><<<dim3(64, 6, 1), 256, 0, stream>>>(
      (const short*)o_b, (const short*)Wo_b, r_f, ob, xq_b, nullptr, ssx,
      768, 768, 768, 768, 1.f, 0, 0, 0, 0, 0);

  ln_kernel<<<8192, 256, 0, stream>>>(r_f, lnw, lnb, out);
}

// Round 11
// 686.481 us; speedup vs baseline: 1.9703x; 1.9703x over previous
//
#include <hip/hip_runtime.h>
#include <hip/hip_bf16.h>

typedef __attribute__((ext_vector_type(8))) short short8;
typedef __attribute__((ext_vector_type(4))) float f32x4;

static __device__ __forceinline__ float b2f(unsigned short u) {
  return __uint_as_float(((unsigned int)u) << 16);
}
static __device__ __forceinline__ unsigned short f2bs(float f) {
  unsigned int u = __float_as_uint(f);
  u = u + 0x7FFFu + ((u >> 16) & 1u);   // RNE (no NaN inputs here)
  return (unsigned short)(u >> 16);
}
// pair f32 -> packed bf16 (HW v_cvt_pk_bf16_f32, RNE)
static __device__ __forceinline__ unsigned int cvt2(float a, float b) {
  __hip_bfloat162 h = __float22bfloat162_rn(make_float2(a, b));
  return *(unsigned int*)&h;
}

// async global->LDS DMA, 16B per lane; LDS dest = wave-uniform base + lane*16
static __device__ __forceinline__ void gload16(const void* g, void* l) {
  __builtin_amdgcn_global_load_lds(
      (const __attribute__((address_space(1))) void*)g,
      (__attribute__((address_space(3))) void*)l, 16, 0, 0);
}

enum { EPI_BF16_SUMSQ = 1, EPI_BF16 = 2, EPI_F32_RESID = 3 };

// ---------------- bf16-A GEMM (m97 structure, proven Round 6) ----------------
// rowscale (raw sumsq): EPI_BF16 -> v = (acc*escale)*rs + bias;
//                       EPI_F32_RESID -> v = acc + bias + rs*resid.
template<int BM, int BN, int EPI, bool XCD1D>
__global__ __launch_bounds__(256, 4) void gemm_bt(
    const short* __restrict__ A, const short* __restrict__ B, void* __restrict__ Cv,
    const float* __restrict__ bias, const unsigned short* __restrict__ residb,
    float* __restrict__ sumsq, const float* __restrict__ rowscale,
    long lda, long ldb, long ldc, int K, float escale,
    long aZ, long bZ, long cZ, int biasZ, int ncolb)
{
  constexpr int BK = 64;
  constexpr int WM = BM / 2, WN = BN / 2, MR = WM / 16, NR = WN / 16;
  __shared__ __align__(16) short As[BM * BK];
  __shared__ __align__(16) short Bs[BN * BK];
  const int t = threadIdx.x;
  const int zb = blockIdx.z;
  long bxc, byp;
  if constexpr (XCD1D) {
    int bid = blockIdx.x;
    int per = gridDim.x >> 3;
    int ppx = per / ncolb;
    int xcd = bid & 7, j = bid >> 3;
    byp = (long)xcd * ppx + j / ncolb;
    bxc = j % ncolb;
  } else {
    byp = blockIdx.x; bxc = blockIdx.y;
  }
  const long row0 = byp * BM;
  const long col0 = bxc * BN;
  const int wave = t >> 6, lane = t & 63;
  const int wr = wave >> 1, wc = wave & 1;
  const int lr = lane & 15, lg = lane >> 4;
  const short* Az = A + (size_t)zb * aZ;
  const short* Bz = B + (size_t)zb * bZ;
  const int lrow8 = lane >> 3;
  const int lgran = (lane & 7) ^ lrow8;

  auto dmaA = [&](int k0) {
    #pragma unroll
    for (int i = 0; i < BM / 32; ++i) {
      int c = wave * (BM / 32) + i;
      gload16(Az + (size_t)(row0 + c * 8 + lrow8) * lda + k0 + lgran * 8,
              &As[c * 512]);
    }
  };
  auto dmaB = [&](int k0) {
    #pragma unroll
    for (int i = 0; i < BN / 32; ++i) {
      int c = wave * (BN / 32) + i;
      gload16(Bz + (size_t)(col0 + c * 8 + lrow8) * ldb + k0 + lgran * 8,
              &Bs[c * 512]);
    }
  };

  const f32x4 zero4 = {0.f, 0.f, 0.f, 0.f};
  f32x4 acc[MR][NR];
  #pragma unroll
  for (int m = 0; m < MR; ++m)
    #pragma unroll
    for (int n = 0; n < NR; ++n) acc[m][n] = zero4;

  dmaA(0); dmaB(0);
  __syncthreads();

  const int nk = K / BK;
  for (int kt = 0; kt < nk; ++kt) {
    #pragma unroll
    for (int kk = 0; kk < 2; ++kk) {
      short8 a[MR], b[NR];
      #pragma unroll
      for (int m = 0; m < MR; ++m) {
        int row = wr * WM + m * 16 + lr, col = kk * 32 + lg * 8;
        a[m] = *(const short8*)&As[row * 64 + (col ^ ((row & 7) << 3))];
      }
      #pragma unroll
      for (int n = 0; n < NR; ++n) {
        int row = wc * WN + n * 16 + lr, col = kk * 32 + lg * 8;
        b[n] = *(const short8*)&Bs[row * 64 + (col ^ ((row & 7) << 3))];
      }
      #pragma unroll
      for (int m = 0; m < MR; ++m)
        #pragma unroll
        for (int n = 0; n < NR; ++n)
          acc[m][n] = __builtin_amdgcn_mfma_f32_16x16x32_bf16(a[m], b[n], acc[m][n], 0, 0, 0);
    }
    if (kt + 1 < nk) {
      __syncthreads();
      dmaA((kt + 1) * BK); dmaB((kt + 1) * BK);
      __syncthreads();
    }
  }

  const float* biasz = bias ? (bias + (size_t)zb * biasZ) : nullptr;
  float* Cf = (float*)Cv;
  unsigned short* Cb = (unsigned short*)Cv;
  #pragma unroll
  for (int m = 0; m < MR; ++m) {
    #pragma unroll
    for (int i = 0; i < 4; ++i) {
      long row = row0 + wr * WM + m * 16 + lg * 4 + i;
      float rs = 1.f;
      if (rowscale) rs = 1.f / (sqrtf(rowscale[row]) + 1e-6f);
      float sq = 0.f;
      #pragma unroll
      for (int n = 0; n < NR; ++n) {
        long col = col0 + wc * WN + n * 16 + lr;
        float v = acc[m][n][i] * escale;
        size_t ci = (size_t)zb * cZ + (size_t)row * ldc + col;
        if constexpr (EPI == EPI_F32_RESID) {
          v += biasz[col] + rs * b2f(residb[(size_t)row * ldc + col]);
          Cf[ci] = v;
        } else if constexpr (EPI == EPI_BF16_SUMSQ) {
          if (biasz) v += biasz[col];
          Cb[ci] = f2bs(v);
          sq += v * v;
        } else {                      // EPI_BF16
          v *= rs;
          if (biasz) v += biasz[col];
          Cb[ci] = f2bs(v);
        }
      }
      if constexpr (EPI == EPI_BF16_SUMSQ) {
        #pragma unroll
        for (int off = 1; off < 16; off <<= 1) sq += __shfl_xor(sq, off);
        if (lr == 0) atomicAdd(&sumsq[row], sq);
      }
    }
  }
}

// -------- f32-A fused GEMM (PROVEN Round-8 structure, BM templated):
// C_bf16[M,768] = A_f32[M,K] @ B_bf16[768,K]^T + bias, + row sumsq.
// A staged raw f32 via global_load_lds, converted to bf16 on fragment read
// with HW cvt_pk. Full-rank granule involution: granule g of row r at slot
// g ^ (r&15) -> conflict-free b128 reads. 2 barriers/K-step, single buffer.
template<int BM, bool XCD1D>
__global__ __launch_bounds__(256, 3) void gemm_af32(
    const float* __restrict__ A, const short* __restrict__ B,
    unsigned short* __restrict__ C, const float* __restrict__ bias,
    float* __restrict__ sumsq, int K, int ncolb)
{
  constexpr int BN = 128, BK = 64, WM = BM / 2, WN = 64, MR = WM / 16, NR = 4;
  __shared__ __align__(16) float Asf[BM * BK];
  __shared__ __align__(16) short Bs[BN * BK];
  const int t = threadIdx.x;
  long bxc, byp;
  if constexpr (XCD1D) {
    int bid = blockIdx.x;
    int per = gridDim.x >> 3;
    int ppx = per / ncolb;
    int xcd = bid & 7, j = bid >> 3;
    byp = (long)xcd * ppx + j / ncolb;
    bxc = j % ncolb;
  } else {
    byp = blockIdx.x; bxc = blockIdx.y;
  }
  const long row0 = byp * BM;
  const long col0 = bxc * BN;
  const int wave = t >> 6, lane = t & 63;
  const int wr = wave >> 1, wc = wave & 1;
  const int lr = lane & 15, lg = lane >> 4;
  const int lrow8 = lane >> 3;
  const int lgran8 = (lane & 7) ^ lrow8;   // B-side (bf16) swizzle
  const int lrow4 = lane >> 4;             // A-side f32: 4 rows per 1KB chunk

  auto dmaAf = [&](int k0) {
    #pragma unroll
    for (int i = 0; i < BM / 16; ++i) {
      int c = wave * (BM / 16) + i;      // 4-row chunk; row = c*4 + lrow4
      // source granule = (lane&15) ^ (row&15); c&3 == i&3 for BM in {64,128}
      int lg16 = (lane & 15) ^ lrow4 ^ ((i & 3) << 2);
      gload16(A + (size_t)(row0 + c * 4 + lrow4) * K + k0 + lg16 * 4,
              &Asf[c * 256]);
    }
  };
  auto dmaB = [&](int k0) {
    #pragma unroll
    for (int i = 0; i < 4; ++i) {
      int c = wave * 4 + i;              // 8-row chunk
      gload16(B + (size_t)(col0 + c * 8 + lrow8) * K + k0 + lgran8 * 8,
              &Bs[c * 512]);
    }
  };

  const f32x4 zero4 = {0.f, 0.f, 0.f, 0.f};
  f32x4 acc[MR][NR];
  #pragma unroll
  for (int m = 0; m < MR; ++m)
    #pragma unroll
    for (int n = 0; n < NR; ++n) acc[m][n] = zero4;

  dmaAf(0); dmaB(0);
  __syncthreads();

  const int nk = K / BK;
  for (int kt = 0; kt < nk; ++kt) {
    #pragma unroll
    for (int kk = 0; kk < 2; ++kk) {
      short8 a[MR], b[NR];
      #pragma unroll
      for (int m = 0; m < MR; ++m) {
        int row = wr * WM + m * 16 + lr;   // row & 15 == lr
        int j0 = kk * 8 + lg * 2;          // f32 16B-granule index (2 per frag)
        float4 lo = *(const float4*)&Asf[row * 64 + ((j0 ^ lr) << 2)];
        float4 hi = *(const float4*)&Asf[row * 64 + (((j0 + 1) ^ lr) << 2)];
        union { short8 s; unsigned int u[4]; } U;
        U.u[0] = cvt2(lo.x, lo.y); U.u[1] = cvt2(lo.z, lo.w);
        U.u[2] = cvt2(hi.x, hi.y); U.u[3] = cvt2(hi.z, hi.w);
        a[m] = U.s;
      }
      #pragma unroll
      for (int n = 0; n < NR; ++n) {
        int row = wc * WN + n * 16 + lr, col = kk * 32 + lg * 8;
        b[n] = *(const short8*)&Bs[row * 64 + (col ^ ((row & 7) << 3))];
      }
      #pragma unroll
      for (int m = 0; m < MR; ++m)
        #pragma unroll
        for (int n = 0; n < NR; ++n)
          acc[m][n] = __builtin_amdgcn_mfma_f32_16x16x32_bf16(a[m], b[n], acc[m][n], 0, 0, 0);
    }
    if (kt + 1 < nk) {
      __syncthreads();
      dmaAf((kt + 1) * BK); dmaB((kt + 1) * BK);
      __syncthreads();
    }
  }

  #pragma unroll
  for (int m = 0; m < MR; ++m) {
    #pragma unroll
    for (int i = 0; i < 4; ++i) {
      long row = row0 + wr * WM + m * 16 + lg * 4 + i;
      float sq = 0.f;
      #pragma unroll
      for (int n = 0; n < NR; ++n) {
        long col = col0 + wc * WN + n * 16 + lr;
        float v = acc[m][n][i] + bias[col];
        C[(size_t)row * 768 + col] = f2bs(v);
        sq += v * v;
      }
      #pragma unroll
      for (int off = 1; off < 16; off <<= 1) sq += __shfl_xor(sq, off);
      if (lr == 0) atomicAdd(&sumsq[row], sq);
    }
  }
}

// all weight conversions in one dispatch
__global__ __launch_bounds__(256) void wconv_kernel(
    const float* __restrict__ Wx, const float* __restrict__ Wy,
    const float* __restrict__ ipw, const float* __restrict__ Wo,
    unsigned short* __restrict__ dWx, unsigned short* __restrict__ dWy,
    unsigned short* __restrict__ dWq, unsigned short* __restrict__ dWkT,
    unsigned short* __restrict__ dWv, unsigned short* __restrict__ dWo)
{
  long i = (long)blockIdx.x * 256 + threadIdx.x;
  if (i < 1179648) { dWx[i] = f2bs(Wx[i]); return; }
  i -= 1179648;
  if (i < 786432) { dWy[i] = f2bs(Wy[i]); return; }
  i -= 786432;
  if (i < 589824) { dWq[i] = f2bs(ipw[i]); return; }
  i -= 589824;
  if (i < 589824) {  // WkT[h][n][j] = Wk[h*64+j][n]
    int h = (int)(i / 49152), r = (int)(i % 49152);
    int nn = r >> 6, j = r & 63;
    dWkT[i] = f2bs(ipw[(size_t)(768 + h * 64 + j) * 768 + nn]);
    return;
  }
  i -= 589824;
  if (i < 589824) { dWv[i] = f2bs(ipw[2 * 589824 + i]); return; }
  i -= 589824;
  if (i < 589824) { dWo[i] = f2bs(Wo[i]); }
}

// Per-token fused: S = (qk . z)*invn -> softmax_w -> a = attn*invn -> u = a @ z
__global__ __launch_bounds__(256) void attn_kernel(
    const unsigned short* __restrict__ z, const unsigned short* __restrict__ qk,
    const float* __restrict__ ssy, unsigned short* __restrict__ u)
{
  __shared__ __align__(16) unsigned short zl[16 * 768];
  __shared__ __align__(16) unsigned short ql[12 * 768];
  __shared__ float sc[3][256];
  __shared__ float al[256];
  __shared__ float il[16];
  const int t = threadIdx.x;
  const long m = blockIdx.x;
  const int wv = t >> 6, lane = t & 63;
  const int lr = lane & 15, lg = lane >> 4;

  for (int s = t; s < 1536; s += 256) {
    int row = s / 96, g = s % 96;
    *(short8*)&zl[row * 768 + ((g ^ (row & 7)) << 3)] =
        *(const short8*)(z + m * 12288 + (size_t)s * 8);
  }
  for (int s = t; s < 1152; s += 256) {
    int row = s / 96, g = s % 96;
    *(short8*)&ql[row * 768 + ((g ^ (row & 7)) << 3)] =
        *(const short8*)(qk + m * 9216 + (size_t)s * 8);
  }
  if (t < 16) il[t] = 1.f / (sqrtf(ssy[m * 16 + t]) + 1e-6f);
  __syncthreads();

  f32x4 c = {0.f, 0.f, 0.f, 0.f};
  #pragma unroll
  for (int i = 0; i < 6; ++i) {
    int gb = wv * 24 + i * 4 + lg;
    short8 a = (lr < 12) ? *(const short8*)&ql[lr * 768 + ((gb ^ (lr & 7)) << 3)]
                         : short8{0, 0, 0, 0, 0, 0, 0, 0};
    short8 b = *(const short8*)&zl[lr * 768 + ((gb ^ (lr & 7)) << 3)];
    c = __builtin_amdgcn_mfma_f32_16x16x32_bf16(a, b, c, 0, 0, 0);
  }
  if (wv > 0) {
    #pragma unroll
    for (int i = 0; i < 4; ++i) sc[wv - 1][(lg * 4 + i) * 16 + lr] = c[i];
  }
  __syncthreads();
  if (wv == 0) {
    #pragma unroll
    for (int i = 0; i < 4; ++i) {
      int idx = (lg * 4 + i) * 16 + lr;
      float s = (c[i] + sc[0][idx] + sc[1][idx] + sc[2][idx]) * il[lr];
      float mx = s;
      #pragma unroll
      for (int off = 1; off < 16; off <<= 1) mx = fmaxf(mx, __shfl_xor(mx, off));
      float e = __expf(s - mx);
      float sum = e;
      #pragma unroll
      for (int off = 1; off < 16; off <<= 1) sum += __shfl_xor(sum, off);
      al[idx] = e / sum * il[lr];
    }
  }
  __syncthreads();

  for (int s = t; s < 1152; s += 256) {
    int h = s / 96, gd = s % 96;
    float acc[8] = {0.f, 0.f, 0.f, 0.f, 0.f, 0.f, 0.f, 0.f};
    #pragma unroll
    for (int w = 0; w < 16; ++w) {
      float aw = al[h * 16 + w];
      short8 zz = *(const short8*)&zl[w * 768 + ((gd ^ (w & 7)) << 3)];
      #pragma unroll
      for (int j = 0; j < 8; ++j) acc[j] += aw * b2f((unsigned short)zz[j]);
    }
    short8 o;
    #pragma unroll
    for (int j = 0; j < 8; ++j) o[j] = (short)f2bs(acc[j]);
    *(short8*)&u[m * 9216 + (size_t)s * 8] = o;
  }
}

__global__ __launch_bounds__(256) void ln_kernel(const float* __restrict__ R,
                                                 const float* __restrict__ w,
                                                 const float* __restrict__ b,
                                                 float* __restrict__ out) {
  const long row = blockIdx.x;
  const int t = threadIdx.x;
  const float* rr = R + row * 768;
  float v0 = rr[t], v1 = rr[t + 256], v2 = rr[t + 512];
  float s = v0 + v1 + v2;
  #pragma unroll
  for (int off = 1; off < 64; off <<= 1) s += __shfl_xor(s, off);
  __shared__ float ps[4];
  __shared__ float ps2[4];
  const int wave = t >> 6, lane = t & 63;
  if (lane == 0) ps[wave] = s;
  __syncthreads();
  const float mean = (ps[0] + ps[1] + ps[2] + ps[3]) * (1.f / 768.f);
  const float d0 = v0 - mean, d1 = v1 - mean, d2 = v2 - mean;
  float q = d0 * d0 + d1 * d1 + d2 * d2;
  #pragma unroll
  for (int off = 1; off < 64; off <<= 1) q += __shfl_xor(q, off);
  if (lane == 0) ps2[wave] = q;
  __syncthreads();
  const float var = (ps2[0] + ps2[1] + ps2[2] + ps2[3]) * (1.f / 768.f);
  const float rs = rsqrtf(var + 1e-6f);
  float* oo = out + row * 768;
  oo[t]       = d0 * rs * w[t]       + b[t];
  oo[t + 256] = d1 * rs * w[t + 256] + b[t + 256];
  oo[t + 512] = d2 * rs * w[t + 512] + b[t + 512];
}

extern "C" void kernel_launch(void* const* d_in, const int* in_sizes, int n_in,
                              void* d_out, int out_size, void* d_ws, size_t ws_size,
                              hipStream_t stream) {
  const float* x   = (const float*)d_in[0];   // (8,1024,1536)
  const float* y   = (const float*)d_in[1];   // (8,16384,1024)
  const float* Wx  = (const float*)d_in[2];   // (768,1536)
  const float* bx  = (const float*)d_in[3];
  const float* Wy  = (const float*)d_in[4];   // (768,1024)
  const float* by  = (const float*)d_in[5];
  const float* ipw = (const float*)d_in[6];   // (2304,768)
  const float* ipb = (const float*)d_in[7];
  const float* Wo  = (const float*)d_in[8];   // (768,768)
  const float* ob  = (const float*)d_in[9];
  const float* lnw = (const float*)d_in[10];
  const float* lnb = (const float*)d_in[11];
  float* out = (float*)d_out;

  char* ws = (char*)d_ws;
  size_t off = 0;
  auto alloc = [&](size_t bytes) {
    void* p = ws + off;
    off += (bytes + 4095) & ~(size_t)4095;
    return p;
  };
  unsigned short* Wx_b  = (unsigned short*)alloc(768L * 1536 * 2);
  unsigned short* Wy_b  = (unsigned short*)alloc(768L * 1024 * 2);
  unsigned short* Wq_b  = (unsigned short*)alloc(768L * 768 * 2);
  unsigned short* WkT_b = (unsigned short*)alloc(768L * 768 * 2);
  unsigned short* Wv_b  = (unsigned short*)alloc(768L * 768 * 2);
  unsigned short* Wo_b  = (unsigned short*)alloc(768L * 768 * 2);
  float* ssx = (float*)alloc(8192L * 4);
  float* ssy = (float*)alloc(131072L * 4);
  unsigned short* z_b  = (unsigned short*)alloc(131072L * 768 * 2);
  unsigned short* xq_b = (unsigned short*)alloc(8192L * 768 * 2);
  char* reg = (char*)alloc(134217728L * 2);    // 256 MB scratch region
  unsigned short* q_b  = (unsigned short*)(reg + 25165824);       // 12.6 MB
  unsigned short* qk_b = (unsigned short*)(reg + 37748736);       // 151 MB (also u)
  unsigned short* o_b  = (unsigned short*)(reg + 188743680);      // 12.6 MB
  float*          r_f  = (float*)(reg + 201326592);               // 25.2 MB
  (void)ws_size; (void)in_sizes; (void)n_in; (void)out_size;

  hipMemsetAsync(ssx, 0, 8192L * 4, stream);
  hipMemsetAsync(ssy, 0, 131072L * 4, stream);

  // all weights -> bf16 in one dispatch (4325376 elems)
  wconv_kernel<<<16896, 256, 0, stream>>>(Wx, Wy, ipw, Wo,
                                          Wx_b, Wy_b, Wq_b, WkT_b, Wv_b, Wo_b);

  // z = y @ Wy^T + by (bf16 + sumsq), f32 A fused, XCD-contiguous panels
  gemm_af32<128, true><<<6144, 256, 0, stream>>>(
      y, (const short*)Wy_b, z_b, by, ssy, 1024, 6);

  // xq_raw = x @ Wx^T + bx (bf16, UNSCALED, + sumsq); BM=64 -> 768 blocks
  gemm_af32<64, false><<<dim3(128, 6, 1), 256, 0, stream>>>(
      x, (const short*)Wx_b, xq_b, bx, ssx, 1536, 0);

  // q = rs[m]*(xq_raw @ Wq^T) + bq   (rowscale folded into epilogue)
  gemm_bt<128, 128, EPI_BF16, false><<<dim3(64, 6, 1), 256, 0, stream>>>(
      (const short*)xq_b, (const short*)Wq_b, q_b, ipb, nullptr, nullptr, ssx,
      768, 768, 768, 768, 1.f, 0, 0, 0, 0, 0);

  // qk[m,h,:] = scale * q[m,h*64:+64] @ WkT[h]   (bk dropped: softmax-invariant)
  gemm_bt<128, 128, EPI_BF16, false><<<dim3(64, 6, 12), 256, 0, stream>>>(
      (const short*)q_b, (const short*)WkT_b, qk_b, nullptr, nullptr, nullptr, nullptr,
      768, 64, 9216, 64, 0.125f, 64, 49152, 768, 0, 0);

  // fused scores/softmax/u  (u overwrites qk slice per token)
  attn_kernel<<<8192, 256, 0, stream>>>(z_b, qk_b, ssy, qk_b);

  // o[:,h*64:+64] = u[:,h,:] @ Wv_h^T + bv_h
  gemm_bt<128, 64, EPI_BF16, false><<<dim3(64, 1, 12), 256, 0, stream>>>(
      (const short*)qk_b, (const short*)Wv_b, o_b, ipb + 1536, nullptr, nullptr, nullptr,
      9216, 768, 768, 768, 1.f, 768, 49152, 64, 64, 0);

  // r = o @ out_w^T + out_b + rs[m]*xq_raw   (residual row-scale in epilogue)
  gemm_bt<128, 128, EPI_F32_RESID, false><<<dim3(64, 6, 1), 256, 0, stream>>>(
      (const short*)o_b, (const short*)Wo_b, r_f, ob, xq_b, nullptr, ssx,
      768, 768, 768, 768, 1.f, 0, 0, 0, 0, 0);

  ln_kernel<<<8192, 256, 0, stream>>>(r_f, lnw, lnb, out);
}

// Round 12
// 676.395 us; speedup vs baseline: 1.9997x; 1.0149x over previous
//
#include <hip/hip_runtime.h>
#include <hip/hip_bf16.h>

typedef __attribute__((ext_vector_type(8))) short short8;
typedef __attribute__((ext_vector_type(4))) float f32x4;

static __device__ __forceinline__ float b2f(unsigned short u) {
  return __uint_as_float(((unsigned int)u) << 16);
}
static __device__ __forceinline__ unsigned short f2bs(float f) {
  unsigned int u = __float_as_uint(f);
  u = u + 0x7FFFu + ((u >> 16) & 1u);   // RNE (no NaN inputs here)
  return (unsigned short)(u >> 16);
}
// pair f32 -> packed bf16 (HW v_cvt_pk_bf16_f32, RNE)
static __device__ __forceinline__ unsigned int cvt2(float a, float b) {
  __hip_bfloat162 h = __float22bfloat162_rn(make_float2(a, b));
  return *(unsigned int*)&h;
}

// async global->LDS DMA, 16B per lane; LDS dest = wave-uniform base + lane*16
static __device__ __forceinline__ void gload16(const void* g, void* l) {
  __builtin_amdgcn_global_load_lds(
      (const __attribute__((address_space(1))) void*)g,
      (__attribute__((address_space(3))) void*)l, 16, 0, 0);
}

enum { EPI_BF16_SUMSQ = 1, EPI_BF16 = 2, EPI_F32_RESID = 3 };

// ---------------- bf16-A GEMM (m97 structure, proven Round 6) ----------------
// rowscale (raw sumsq): EPI_BF16 -> v = (acc*escale)*rs + bias;
//                       EPI_F32_RESID -> v = acc + bias + rs*resid.
template<int BM, int BN, int EPI, bool XCD1D>
__global__ __launch_bounds__(256, 4) void gemm_bt(
    const short* __restrict__ A, const short* __restrict__ B, void* __restrict__ Cv,
    const float* __restrict__ bias, const unsigned short* __restrict__ residb,
    float* __restrict__ sumsq, const float* __restrict__ rowscale,
    long lda, long ldb, long ldc, int K, float escale,
    long aZ, long bZ, long cZ, int biasZ, int ncolb)
{
  constexpr int BK = 64;
  constexpr int WM = BM / 2, WN = BN / 2, MR = WM / 16, NR = WN / 16;
  __shared__ __align__(16) short As[BM * BK];
  __shared__ __align__(16) short Bs[BN * BK];
  const int t = threadIdx.x;
  const int zb = blockIdx.z;
  long bxc, byp;
  if constexpr (XCD1D) {
    int bid = blockIdx.x;
    int per = gridDim.x >> 3;
    int ppx = per / ncolb;
    int xcd = bid & 7, j = bid >> 3;
    byp = (long)xcd * ppx + j / ncolb;
    bxc = j % ncolb;
  } else {
    byp = blockIdx.x; bxc = blockIdx.y;
  }
  const long row0 = byp * BM;
  const long col0 = bxc * BN;
  const int wave = t >> 6, lane = t & 63;
  const int wr = wave >> 1, wc = wave & 1;
  const int lr = lane & 15, lg = lane >> 4;
  const short* Az = A + (size_t)zb * aZ;
  const short* Bz = B + (size_t)zb * bZ;
  const int lrow8 = lane >> 3;
  const int lgran = (lane & 7) ^ lrow8;

  auto dmaA = [&](int k0) {
    #pragma unroll
    for (int i = 0; i < BM / 32; ++i) {
      int c = wave * (BM / 32) + i;
      gload16(Az + (size_t)(row0 + c * 8 + lrow8) * lda + k0 + lgran * 8,
              &As[c * 512]);
    }
  };
  auto dmaB = [&](int k0) {
    #pragma unroll
    for (int i = 0; i < BN / 32; ++i) {
      int c = wave * (BN / 32) + i;
      gload16(Bz + (size_t)(col0 + c * 8 + lrow8) * ldb + k0 + lgran * 8,
              &Bs[c * 512]);
    }
  };

  const f32x4 zero4 = {0.f, 0.f, 0.f, 0.f};
  f32x4 acc[MR][NR];
  #pragma unroll
  for (int m = 0; m < MR; ++m)
    #pragma unroll
    for (int n = 0; n < NR; ++n) acc[m][n] = zero4;

  dmaA(0); dmaB(0);
  __syncthreads();

  const int nk = K / BK;
  for (int kt = 0; kt < nk; ++kt) {
    #pragma unroll
    for (int kk = 0; kk < 2; ++kk) {
      short8 a[MR], b[NR];
      #pragma unroll
      for (int m = 0; m < MR; ++m) {
        int row = wr * WM + m * 16 + lr, col = kk * 32 + lg * 8;
        a[m] = *(const short8*)&As[row * 64 + (col ^ ((row & 7) << 3))];
      }
      #pragma unroll
      for (int n = 0; n < NR; ++n) {
        int row = wc * WN + n * 16 + lr, col = kk * 32 + lg * 8;
        b[n] = *(const short8*)&Bs[row * 64 + (col ^ ((row & 7) << 3))];
      }
      #pragma unroll
      for (int m = 0; m < MR; ++m)
        #pragma unroll
        for (int n = 0; n < NR; ++n)
          acc[m][n] = __builtin_amdgcn_mfma_f32_16x16x32_bf16(a[m], b[n], acc[m][n], 0, 0, 0);
    }
    if (kt + 1 < nk) {
      __syncthreads();
      dmaA((kt + 1) * BK); dmaB((kt + 1) * BK);
      __syncthreads();
    }
  }

  const float* biasz = bias ? (bias + (size_t)zb * biasZ) : nullptr;
  float* Cf = (float*)Cv;
  unsigned short* Cb = (unsigned short*)Cv;
  #pragma unroll
  for (int m = 0; m < MR; ++m) {
    #pragma unroll
    for (int i = 0; i < 4; ++i) {
      long row = row0 + wr * WM + m * 16 + lg * 4 + i;
      float rs = 1.f;
      if (rowscale) rs = 1.f / (sqrtf(rowscale[row]) + 1e-6f);
      float sq = 0.f;
      #pragma unroll
      for (int n = 0; n < NR; ++n) {
        long col = col0 + wc * WN + n * 16 + lr;
        float v = acc[m][n][i] * escale;
        size_t ci = (size_t)zb * cZ + (size_t)row * ldc + col;
        if constexpr (EPI == EPI_F32_RESID) {
          v += biasz[col] + rs * b2f(residb[(size_t)row * ldc + col]);
          Cf[ci] = v;
        } else if constexpr (EPI == EPI_BF16_SUMSQ) {
          if (biasz) v += biasz[col];
          Cb[ci] = f2bs(v);
          sq += v * v;
        } else {                      // EPI_BF16
          v *= rs;
          if (biasz) v += biasz[col];
          Cb[ci] = f2bs(v);
        }
      }
      if constexpr (EPI == EPI_BF16_SUMSQ) {
        #pragma unroll
        for (int off = 1; off < 16; off <<= 1) sq += __shfl_xor(sq, off);
        if (lr == 0) atomicAdd(&sumsq[row], sq);
      }
    }
  }
}

// -------- f32-A fused GEMM (PROVEN Round-8 structure), DUAL dispatch:
// blocks [0,nz): z path (XCD1D mapping over nz blocks);
// blocks [nz,..): x path (linear, 6 col-blocks). Same structure both.
// C_bf16[M,768] = A_f32[M,K] @ B_bf16[768,K]^T + bias, + row sumsq.
// A staged raw f32 via global_load_lds, converted to bf16 on fragment read
// with HW cvt_pk. Full-rank granule involution: granule g of row r at slot
// g ^ (r&15) -> conflict-free b128 reads. 2 barriers/K-step, single buffer.
__global__ __launch_bounds__(256, 3) void gemm_af32_dual(
    const float* __restrict__ A, const short* __restrict__ B,
    unsigned short* __restrict__ C, const float* __restrict__ bias,
    float* __restrict__ sumsq, int K, int ncolb, int nz,
    const float* __restrict__ A2, const short* __restrict__ B2,
    unsigned short* __restrict__ C2, const float* __restrict__ bias2,
    float* __restrict__ sumsq2, int K2)
{
  constexpr int BM = 128, BN = 128, BK = 64, WM = 64, WN = 64, MR = 4, NR = 4;
  __shared__ __align__(16) float Asf[BM * BK];
  __shared__ __align__(16) short Bs[BN * BK];
  const int t = threadIdx.x;
  const int bid = blockIdx.x;

  const float* Ap; const short* Bp; unsigned short* Cp;
  const float* biasp; float* ssp; int Kl;
  long bxc, byp;
  if (bid < nz) {              // z path: XCD1D over nz blocks
    int per = nz >> 3;
    int ppx = per / ncolb;
    int xcd = bid & 7, j = bid >> 3;
    byp = (long)xcd * ppx + j / ncolb;
    bxc = j % ncolb;
    Ap = A; Bp = B; Cp = C; biasp = bias; ssp = sumsq; Kl = K;
  } else {                     // x path: linear, 6 col-blocks
    int j = bid - nz;
    byp = j / 6; bxc = j % 6;
    Ap = A2; Bp = B2; Cp = C2; biasp = bias2; ssp = sumsq2; Kl = K2;
  }
  const long row0 = byp * BM;
  const long col0 = bxc * BN;
  const int wave = t >> 6, lane = t & 63;
  const int wr = wave >> 1, wc = wave & 1;
  const int lr = lane & 15, lg = lane >> 4;
  const int lrow8 = lane >> 3;
  const int lgran8 = (lane & 7) ^ lrow8;   // B-side (bf16) swizzle
  const int lrow4 = lane >> 4;             // A-side f32: 4 rows per 1KB chunk

  auto dmaAf = [&](int k0) {
    #pragma unroll
    for (int i = 0; i < BM / 16; ++i) {
      int c = wave * (BM / 16) + i;      // 4-row chunk; row = c*4 + lrow4
      // source granule = (lane&15) ^ (row&15); c&3 == i&3 (wave*8 ≡ 0 mod 4)
      int lg16 = (lane & 15) ^ lrow4 ^ ((i & 3) << 2);
      gload16(Ap + (size_t)(row0 + c * 4 + lrow4) * Kl + k0 + lg16 * 4,
              &Asf[c * 256]);
    }
  };
  auto dmaB = [&](int k0) {
    #pragma unroll
    for (int i = 0; i < 4; ++i) {
      int c = wave * 4 + i;              // 8-row chunk
      gload16(Bp + (size_t)(col0 + c * 8 + lrow8) * Kl + k0 + lgran8 * 8,
              &Bs[c * 512]);
    }
  };

  const f32x4 zero4 = {0.f, 0.f, 0.f, 0.f};
  f32x4 acc[MR][NR];
  #pragma unroll
  for (int m = 0; m < MR; ++m)
    #pragma unroll
    for (int n = 0; n < NR; ++n) acc[m][n] = zero4;

  dmaAf(0); dmaB(0);
  __syncthreads();

  const int nk = Kl / BK;
  for (int kt = 0; kt < nk; ++kt) {
    #pragma unroll
    for (int kk = 0; kk < 2; ++kk) {
      short8 a[MR], b[NR];
      #pragma unroll
      for (int m = 0; m < MR; ++m) {
        int row = wr * WM + m * 16 + lr;   // row & 15 == lr
        int j0 = kk * 8 + lg * 2;          // f32 16B-granule index (2 per frag)
        float4 lo = *(const float4*)&Asf[row * 64 + ((j0 ^ lr) << 2)];
        float4 hi = *(const float4*)&Asf[row * 64 + (((j0 + 1) ^ lr) << 2)];
        union { short8 s; unsigned int u[4]; } U;
        U.u[0] = cvt2(lo.x, lo.y); U.u[1] = cvt2(lo.z, lo.w);
        U.u[2] = cvt2(hi.x, hi.y); U.u[3] = cvt2(hi.z, hi.w);
        a[m] = U.s;
      }
      #pragma unroll
      for (int n = 0; n < NR; ++n) {
        int row = wc * WN + n * 16 + lr, col = kk * 32 + lg * 8;
        b[n] = *(const short8*)&Bs[row * 64 + (col ^ ((row & 7) << 3))];
      }
      #pragma unroll
      for (int m = 0; m < MR; ++m)
        #pragma unroll
        for (int n = 0; n < NR; ++n)
          acc[m][n] = __builtin_amdgcn_mfma_f32_16x16x32_bf16(a[m], b[n], acc[m][n], 0, 0, 0);
    }
    if (kt + 1 < nk) {
      __syncthreads();
      dmaAf((kt + 1) * BK); dmaB((kt + 1) * BK);
      __syncthreads();
    }
  }

  #pragma unroll
  for (int m = 0; m < MR; ++m) {
    #pragma unroll
    for (int i = 0; i < 4; ++i) {
      long row = row0 + wr * WM + m * 16 + lg * 4 + i;
      float sq = 0.f;
      #pragma unroll
      for (int n = 0; n < NR; ++n) {
        long col = col0 + wc * WN + n * 16 + lr;
        float v = acc[m][n][i] + biasp[col];
        Cp[(size_t)row * 768 + col] = f2bs(v);
        sq += v * v;
      }
      #pragma unroll
      for (int off = 1; off < 16; off <<= 1) sq += __shfl_xor(sq, off);
      if (lr == 0) atomicAdd(&ssp[row], sq);
    }
  }
}

// all weight conversions in one dispatch
__global__ __launch_bounds__(256) void wconv_kernel(
    const float* __restrict__ Wx, const float* __restrict__ Wy,
    const float* __restrict__ ipw, const float* __restrict__ Wo,
    unsigned short* __restrict__ dWx, unsigned short* __restrict__ dWy,
    unsigned short* __restrict__ dWq, unsigned short* __restrict__ dWkT,
    unsigned short* __restrict__ dWv, unsigned short* __restrict__ dWo)
{
  long i = (long)blockIdx.x * 256 + threadIdx.x;
  if (i < 1179648) { dWx[i] = f2bs(Wx[i]); return; }
  i -= 1179648;
  if (i < 786432) { dWy[i] = f2bs(Wy[i]); return; }
  i -= 786432;
  if (i < 589824) { dWq[i] = f2bs(ipw[i]); return; }
  i -= 589824;
  if (i < 589824) {  // WkT[h][n][j] = Wk[h*64+j][n]
    int h = (int)(i / 49152), r = (int)(i % 49152);
    int nn = r >> 6, j = r & 63;
    dWkT[i] = f2bs(ipw[(size_t)(768 + h * 64 + j) * 768 + nn]);
    return;
  }
  i -= 589824;
  if (i < 589824) { dWv[i] = f2bs(ipw[2 * 589824 + i]); return; }
  i -= 589824;
  if (i < 589824) { dWo[i] = f2bs(Wo[i]); }
}

// Per-token fused: S = (qk . z)*invn -> softmax_w -> a = attn*invn -> u = a @ z
__global__ __launch_bounds__(256) void attn_kernel(
    const unsigned short* __restrict__ z, const unsigned short* __restrict__ qk,
    const float* __restrict__ ssy, unsigned short* __restrict__ u)
{
  __shared__ __align__(16) unsigned short zl[16 * 768];
  __shared__ __align__(16) unsigned short ql[12 * 768];
  __shared__ float sc[3][256];
  __shared__ float al[256];
  __shared__ float il[16];
  const int t = threadIdx.x;
  const long m = blockIdx.x;
  const int wv = t >> 6, lane = t & 63;
  const int lr = lane & 15, lg = lane >> 4;

  for (int s = t; s < 1536; s += 256) {
    int row = s / 96, g = s % 96;
    *(short8*)&zl[row * 768 + ((g ^ (row & 7)) << 3)] =
        *(const short8*)(z + m * 12288 + (size_t)s * 8);
  }
  for (int s = t; s < 1152; s += 256) {
    int row = s / 96, g = s % 96;
    *(short8*)&ql[row * 768 + ((g ^ (row & 7)) << 3)] =
        *(const short8*)(qk + m * 9216 + (size_t)s * 8);
  }
  if (t < 16) il[t] = 1.f / (sqrtf(ssy[m * 16 + t]) + 1e-6f);
  __syncthreads();

  f32x4 c = {0.f, 0.f, 0.f, 0.f};
  #pragma unroll
  for (int i = 0; i < 6; ++i) {
    int gb = wv * 24 + i * 4 + lg;
    short8 a = (lr < 12) ? *(const short8*)&ql[lr * 768 + ((gb ^ (lr & 7)) << 3)]
                         : short8{0, 0, 0, 0, 0, 0, 0, 0};
    short8 b = *(const short8*)&zl[lr * 768 + ((gb ^ (lr & 7)) << 3)];
    c = __builtin_amdgcn_mfma_f32_16x16x32_bf16(a, b, c, 0, 0, 0);
  }
  if (wv > 0) {
    #pragma unroll
    for (int i = 0; i < 4; ++i) sc[wv - 1][(lg * 4 + i) * 16 + lr] = c[i];
  }
  __syncthreads();
  if (wv == 0) {
    #pragma unroll
    for (int i = 0; i < 4; ++i) {
      int idx = (lg * 4 + i) * 16 + lr;
      float s = (c[i] + sc[0][idx] + sc[1][idx] + sc[2][idx]) * il[lr];
      float mx = s;
      #pragma unroll
      for (int off = 1; off < 16; off <<= 1) mx = fmaxf(mx, __shfl_xor(mx, off));
      float e = __expf(s - mx);
      float sum = e;
      #pragma unroll
      for (int off = 1; off < 16; off <<= 1) sum += __shfl_xor(sum, off);
      al[idx] = e / sum * il[lr];
    }
  }
  __syncthreads();

  for (int s = t; s < 1152; s += 256) {
    int h = s / 96, gd = s % 96;
    float acc[8] = {0.f, 0.f, 0.f, 0.f, 0.f, 0.f, 0.f, 0.f};
    #pragma unroll
    for (int w = 0; w < 16; ++w) {
      float aw = al[h * 16 + w];
      short8 zz = *(const short8*)&zl[w * 768 + ((gd ^ (w & 7)) << 3)];
      #pragma unroll
      for (int j = 0; j < 8; ++j) acc[j] += aw * b2f((unsigned short)zz[j]);
    }
    short8 o;
    #pragma unroll
    for (int j = 0; j < 8; ++j) o[j] = (short)f2bs(acc[j]);
    *(short8*)&u[m * 9216 + (size_t)s * 8] = o;
  }
}

__global__ __launch_bounds__(256) void ln_kernel(const float* __restrict__ R,
                                                 const float* __restrict__ w,
                                                 const float* __restrict__ b,
                                                 float* __restrict__ out) {
  const long row = blockIdx.x;
  const int t = threadIdx.x;
  const float* rr = R + row * 768;
  float v0 = rr[t], v1 = rr[t + 256], v2 = rr[t + 512];
  float s = v0 + v1 + v2;
  #pragma unroll
  for (int off = 1; off < 64; off <<= 1) s += __shfl_xor(s, off);
  __shared__ float ps[4];
  __shared__ float ps2[4];
  const int wave = t >> 6, lane = t & 63;
  if (lane == 0) ps[wave] = s;
  __syncthreads();
  const float mean = (ps[0] + ps[1] + ps[2] + ps[3]) * (1.f / 768.f);
  const float d0 = v0 - mean, d1 = v1 - mean, d2 = v2 - mean;
  float q = d0 * d0 + d1 * d1 + d2 * d2;
  #pragma unroll
  for (int off = 1; off < 64; off <<= 1) q += __shfl_xor(q, off);
  if (lane == 0) ps2[wave] = q;
  __syncthreads();
  const float var = (ps2[0] + ps2[1] + ps2[2] + ps2[3]) * (1.f / 768.f);
  const float rs = rsqrtf(var + 1e-6f);
  float* oo = out + row * 768;
  oo[t]       = d0 * rs * w[t]       + b[t];
  oo[t + 256] = d1 * rs * w[t + 256] + b[t + 256];
  oo[t + 512] = d2 * rs * w[t + 512] + b[t + 512];
}

extern "C" void kernel_launch(void* const* d_in, const int* in_sizes, int n_in,
                              void* d_out, int out_size, void* d_ws, size_t ws_size,
                              hipStream_t stream) {
  const float* x   = (const float*)d_in[0];   // (8,1024,1536)
  const float* y   = (const float*)d_in[1];   // (8,16384,1024)
  const float* Wx  = (const float*)d_in[2];   // (768,1536)
  const float* bx  = (const float*)d_in[3];
  const float* Wy  = (const float*)d_in[4];   // (768,1024)
  const float* by  = (const float*)d_in[5];
  const float* ipw = (const float*)d_in[6];   // (2304,768)
  const float* ipb = (const float*)d_in[7];
  const float* Wo  = (const float*)d_in[8];   // (768,768)
  const float* ob  = (const float*)d_in[9];
  const float* lnw = (const float*)d_in[10];
  const float* lnb = (const float*)d_in[11];
  float* out = (float*)d_out;

  char* ws = (char*)d_ws;
  size_t off = 0;
  auto alloc = [&](size_t bytes) {
    void* p = ws + off;
    off += (bytes + 4095) & ~(size_t)4095;
    return p;
  };
  unsigned short* Wx_b  = (unsigned short*)alloc(768L * 1536 * 2);
  unsigned short* Wy_b  = (unsigned short*)alloc(768L * 1024 * 2);
  unsigned short* Wq_b  = (unsigned short*)alloc(768L * 768 * 2);
  unsigned short* WkT_b = (unsigned short*)alloc(768L * 768 * 2);
  unsigned short* Wv_b  = (unsigned short*)alloc(768L * 768 * 2);
  unsigned short* Wo_b  = (unsigned short*)alloc(768L * 768 * 2);
  float* ssx = (float*)alloc(8192L * 4);
  float* ssy = (float*)alloc(131072L * 4);
  unsigned short* z_b  = (unsigned short*)alloc(131072L * 768 * 2);
  unsigned short* xq_b = (unsigned short*)alloc(8192L * 768 * 2);
  char* reg = (char*)alloc(134217728L * 2);    // 256 MB scratch region
  unsigned short* q_b  = (unsigned short*)(reg + 25165824);       // 12.6 MB
  unsigned short* qk_b = (unsigned short*)(reg + 37748736);       // 151 MB (also u)
  unsigned short* o_b  = (unsigned short*)(reg + 188743680);      // 12.6 MB
  float*          r_f  = (float*)(reg + 201326592);               // 25.2 MB
  (void)ws_size; (void)in_sizes; (void)n_in; (void)out_size;

  hipMemsetAsync(ssx, 0, 8192L * 4, stream);
  hipMemsetAsync(ssy, 0, 131072L * 4, stream);

  // all weights -> bf16 in one dispatch (4325376 elems)
  wconv_kernel<<<16896, 256, 0, stream>>>(Wx, Wy, ipw, Wo,
                                          Wx_b, Wy_b, Wq_b, WkT_b, Wv_b, Wo_b);

  // merged dispatch: blocks [0,6144) z = y@Wy^T+by (XCD1D);
  //                  blocks [6144,6528) xq_raw = x@Wx^T+bx. Both + row sumsq.
  gemm_af32_dual<<<6528, 256, 0, stream>>>(
      y, (const short*)Wy_b, z_b, by, ssy, 1024, 6, 6144,
      x, (const short*)Wx_b, xq_b, bx, ssx, 1536);

  // q = rs[m]*(xq_raw @ Wq^T) + bq   (rowscale folded into epilogue), BM=64
  gemm_bt<64, 128, EPI_BF16, false><<<dim3(128, 6, 1), 256, 0, stream>>>(
      (const short*)xq_b, (const short*)Wq_b, q_b, ipb, nullptr, nullptr, ssx,
      768, 768, 768, 768, 1.f, 0, 0, 0, 0, 0);

  // qk[m,h,:] = scale * q[m,h*64:+64] @ WkT[h]   (bk dropped: softmax-invariant)
  gemm_bt<128, 128, EPI_BF16, false><<<dim3(64, 6, 12), 256, 0, stream>>>(
      (const short*)q_b, (const short*)WkT_b, qk_b, nullptr, nullptr, nullptr, nullptr,
      768, 64, 9216, 64, 0.125f, 64, 49152, 768, 0, 0);

  // fused scores/softmax/u  (u overwrites qk slice per token)
  attn_kernel<<<8192, 256, 0, stream>>>(z_b, qk_b, ssy, qk_b);

  // o[:,h*64:+64] = u[:,h,:] @ Wv_h^T + bv_h
  gemm_bt<128, 64, EPI_BF16, false><<<dim3(64, 1, 12), 256, 0, stream>>>(
      (const short*)qk_b, (const short*)Wv_b, o_b, ipb + 1536, nullptr, nullptr, nullptr,
      9216, 768, 768, 768, 1.f, 768, 49152, 64, 64, 0);

  // r = o @ out_w^T + out_b + rs[m]*xq_raw   (residual row-scale), BM=64
  gemm_bt<64, 128, EPI_F32_RESID, false><<<dim3(128, 6, 1), 256, 0, stream>>>(
      (const short*)o_b, (const short*)Wo_b, r_f, ob, xq_b, nullptr, ssx,
      768, 768, 768, 768, 1.f, 0, 0, 0, 0, 0);

  ln_kernel<<<8192, 256, 0, stream>>>(r_f, lnw, lnb, out);
}

// Round 13
// 668.833 us; speedup vs baseline: 2.0223x; 1.0113x over previous
//
#include <hip/hip_runtime.h>
#include <hip/hip_bf16.h>

typedef __attribute__((ext_vector_type(8))) short short8;
typedef __attribute__((ext_vector_type(4))) float f32x4;

static __device__ __forceinline__ float b2f(unsigned short u) {
  return __uint_as_float(((unsigned int)u) << 16);
}
static __device__ __forceinline__ unsigned short f2bs(float f) {
  unsigned int u = __float_as_uint(f);
  u = u + 0x7FFFu + ((u >> 16) & 1u);   // RNE (no NaN inputs here)
  return (unsigned short)(u >> 16);
}
// pair f32 -> packed bf16 (HW v_cvt_pk_bf16_f32, RNE)
static __device__ __forceinline__ unsigned int cvt2(float a, float b) {
  __hip_bfloat162 h = __float22bfloat162_rn(make_float2(a, b));
  return *(unsigned int*)&h;
}

// async global->LDS DMA, 16B per lane; LDS dest = wave-uniform base + lane*16
static __device__ __forceinline__ void gload16(const void* g, void* l) {
  __builtin_amdgcn_global_load_lds(
      (const __attribute__((address_space(1))) void*)g,
      (__attribute__((address_space(3))) void*)l, 16, 0, 0);
}

enum { EPI_BF16_SUMSQ = 1, EPI_BF16 = 2, EPI_F32_RESID = 3 };

// ---------------- bf16-A GEMM (m97 structure, proven Round 6) ----------------
// rowscale (raw sumsq): EPI_BF16 -> v = (acc*escale)*rs + bias;
//                       EPI_F32_RESID -> v = acc + bias + rs*resid.
template<int BM, int BN, int EPI, bool XCD1D>
__global__ __launch_bounds__(256, 4) void gemm_bt(
    const short* __restrict__ A, const short* __restrict__ B, void* __restrict__ Cv,
    const float* __restrict__ bias, const unsigned short* __restrict__ residb,
    float* __restrict__ sumsq, const float* __restrict__ rowscale,
    long lda, long ldb, long ldc, int K, float escale,
    long aZ, long bZ, long cZ, int biasZ, int ncolb)
{
  constexpr int BK = 64;
  constexpr int WM = BM / 2, WN = BN / 2, MR = WM / 16, NR = WN / 16;
  __shared__ __align__(16) short As[BM * BK];
  __shared__ __align__(16) short Bs[BN * BK];
  const int t = threadIdx.x;
  const int zb = blockIdx.z;
  long bxc, byp;
  if constexpr (XCD1D) {
    int bid = blockIdx.x;
    int per = gridDim.x >> 3;
    int ppx = per / ncolb;
    int xcd = bid & 7, j = bid >> 3;
    byp = (long)xcd * ppx + j / ncolb;
    bxc = j % ncolb;
  } else {
    byp = blockIdx.x; bxc = blockIdx.y;
  }
  const long row0 = byp * BM;
  const long col0 = bxc * BN;
  const int wave = t >> 6, lane = t & 63;
  const int wr = wave >> 1, wc = wave & 1;
  const int lr = lane & 15, lg = lane >> 4;
  const short* Az = A + (size_t)zb * aZ;
  const short* Bz = B + (size_t)zb * bZ;
  const int lrow8 = lane >> 3;
  const int lgran = (lane & 7) ^ lrow8;

  auto dmaA = [&](int k0) {
    #pragma unroll
    for (int i = 0; i < BM / 32; ++i) {
      int c = wave * (BM / 32) + i;
      gload16(Az + (size_t)(row0 + c * 8 + lrow8) * lda + k0 + lgran * 8,
              &As[c * 512]);
    }
  };
  auto dmaB = [&](int k0) {
    #pragma unroll
    for (int i = 0; i < BN / 32; ++i) {
      int c = wave * (BN / 32) + i;
      gload16(Bz + (size_t)(col0 + c * 8 + lrow8) * ldb + k0 + lgran * 8,
              &Bs[c * 512]);
    }
  };

  const f32x4 zero4 = {0.f, 0.f, 0.f, 0.f};
  f32x4 acc[MR][NR];
  #pragma unroll
  for (int m = 0; m < MR; ++m)
    #pragma unroll
    for (int n = 0; n < NR; ++n) acc[m][n] = zero4;

  dmaA(0); dmaB(0);
  __syncthreads();

  const int nk = K / BK;
  for (int kt = 0; kt < nk; ++kt) {
    #pragma unroll
    for (int kk = 0; kk < 2; ++kk) {
      short8 a[MR], b[NR];
      #pragma unroll
      for (int m = 0; m < MR; ++m) {
        int row = wr * WM + m * 16 + lr, col = kk * 32 + lg * 8;
        a[m] = *(const short8*)&As[row * 64 + (col ^ ((row & 7) << 3))];
      }
      #pragma unroll
      for (int n = 0; n < NR; ++n) {
        int row = wc * WN + n * 16 + lr, col = kk * 32 + lg * 8;
        b[n] = *(const short8*)&Bs[row * 64 + (col ^ ((row & 7) << 3))];
      }
      #pragma unroll
      for (int m = 0; m < MR; ++m)
        #pragma unroll
        for (int n = 0; n < NR; ++n)
          acc[m][n] = __builtin_amdgcn_mfma_f32_16x16x32_bf16(a[m], b[n], acc[m][n], 0, 0, 0);
    }
    if (kt + 1 < nk) {
      __syncthreads();
      dmaA((kt + 1) * BK); dmaB((kt + 1) * BK);
      __syncthreads();
    }
  }

  const float* biasz = bias ? (bias + (size_t)zb * biasZ) : nullptr;
  float* Cf = (float*)Cv;
  unsigned short* Cb = (unsigned short*)Cv;
  #pragma unroll
  for (int m = 0; m < MR; ++m) {
    #pragma unroll
    for (int i = 0; i < 4; ++i) {
      long row = row0 + wr * WM + m * 16 + lg * 4 + i;
      float rs = 1.f;
      if (rowscale) rs = 1.f / (sqrtf(rowscale[row]) + 1e-6f);
      float sq = 0.f;
      #pragma unroll
      for (int n = 0; n < NR; ++n) {
        long col = col0 + wc * WN + n * 16 + lr;
        float v = acc[m][n][i] * escale;
        size_t ci = (size_t)zb * cZ + (size_t)row * ldc + col;
        if constexpr (EPI == EPI_F32_RESID) {
          v += biasz[col] + rs * b2f(residb[(size_t)row * ldc + col]);
          Cf[ci] = v;
        } else if constexpr (EPI == EPI_BF16_SUMSQ) {
          if (biasz) v += biasz[col];
          Cb[ci] = f2bs(v);
          sq += v * v;
        } else {                      // EPI_BF16
          v *= rs;
          if (biasz) v += biasz[col];
          Cb[ci] = f2bs(v);
        }
      }
      if constexpr (EPI == EPI_BF16_SUMSQ) {
        #pragma unroll
        for (int off = 1; off < 16; off <<= 1) sq += __shfl_xor(sq, off);
        if (lr == 0) atomicAdd(&sumsq[row], sq);
      }
    }
  }
}

// -------- f32-A fused GEMM (Round-8 structure, 4x1 WAVE SPLIT), DUAL dispatch:
// blocks [0,nz): z path (XCD1D mapping over nz blocks);
// blocks [nz,..): x path (linear, 6 col-blocks). Same structure both.
// 4x1 split: wave w owns rows [32w,32w+32) x all 128 cols (MR=2,NR=8) ->
// A-frag LDS reads and cvt_pk HALVED vs 2x2 (no duplicate A work per row-pair).
// A staged raw f32 via global_load_lds, bf16-converted on fragment read.
// Full-rank granule involution: slot g ^ (r&15) -> conflict-free b128 reads.
__global__ __launch_bounds__(256, 3) void gemm_af32_dual(
    const float* __restrict__ A, const short* __restrict__ B,
    unsigned short* __restrict__ C, const float* __restrict__ bias,
    float* __restrict__ sumsq, int K, int ncolb, int nz,
    const float* __restrict__ A2, const short* __restrict__ B2,
    unsigned short* __restrict__ C2, const float* __restrict__ bias2,
    float* __restrict__ sumsq2, int K2)
{
  constexpr int BM = 128, BN = 128, BK = 64, WM = 32, MR = 2, NR = 8;
  __shared__ __align__(16) float Asf[BM * BK];
  __shared__ __align__(16) short Bs[BN * BK];
  const int t = threadIdx.x;
  const int bid = blockIdx.x;

  const float* Ap; const short* Bp; unsigned short* Cp;
  const float* biasp; float* ssp; int Kl;
  long bxc, byp;
  if (bid < nz) {              // z path: XCD1D over nz blocks
    int per = nz >> 3;
    int ppx = per / ncolb;
    int xcd = bid & 7, j = bid >> 3;
    byp = (long)xcd * ppx + j / ncolb;
    bxc = j % ncolb;
    Ap = A; Bp = B; Cp = C; biasp = bias; ssp = sumsq; Kl = K;
  } else {                     // x path: linear, 6 col-blocks
    int j = bid - nz;
    byp = j / 6; bxc = j % 6;
    Ap = A2; Bp = B2; Cp = C2; biasp = bias2; ssp = sumsq2; Kl = K2;
  }
  const long row0 = byp * BM;
  const long col0 = bxc * BN;
  const int wave = t >> 6, lane = t & 63;
  const int lr = lane & 15, lg = lane >> 4;
  const int lrow8 = lane >> 3;
  const int lgran8 = (lane & 7) ^ lrow8;   // B-side (bf16) swizzle
  const int lrow4 = lane >> 4;             // A-side f32: 4 rows per 1KB chunk

  auto dmaAf = [&](int k0) {
    #pragma unroll
    for (int i = 0; i < BM / 16; ++i) {
      int c = wave * (BM / 16) + i;      // 4-row chunk; row = c*4 + lrow4
      // source granule = (lane&15) ^ (row&15); c&3 == i&3 (wave*8 ≡ 0 mod 4)
      int lg16 = (lane & 15) ^ lrow4 ^ ((i & 3) << 2);
      gload16(Ap + (size_t)(row0 + c * 4 + lrow4) * Kl + k0 + lg16 * 4,
              &Asf[c * 256]);
    }
  };
  auto dmaB = [&](int k0) {
    #pragma unroll
    for (int i = 0; i < 4; ++i) {
      int c = wave * 4 + i;              // 8-row chunk
      gload16(Bp + (size_t)(col0 + c * 8 + lrow8) * Kl + k0 + lgran8 * 8,
              &Bs[c * 512]);
    }
  };

  const f32x4 zero4 = {0.f, 0.f, 0.f, 0.f};
  f32x4 acc[MR][NR];
  #pragma unroll
  for (int m = 0; m < MR; ++m)
    #pragma unroll
    for (int n = 0; n < NR; ++n) acc[m][n] = zero4;

  dmaAf(0); dmaB(0);
  __syncthreads();

  const int nk = Kl / BK;
  for (int kt = 0; kt < nk; ++kt) {
    #pragma unroll
    for (int kk = 0; kk < 2; ++kk) {
      short8 a[MR], b[NR];
      #pragma unroll
      for (int m = 0; m < MR; ++m) {
        int row = wave * WM + m * 16 + lr;  // row & 15 == lr
        int j0 = kk * 8 + lg * 2;           // f32 16B-granule index (2 per frag)
        float4 lo = *(const float4*)&Asf[row * 64 + ((j0 ^ lr) << 2)];
        float4 hi = *(const float4*)&Asf[row * 64 + (((j0 + 1) ^ lr) << 2)];
        union { short8 s; unsigned int u[4]; } U;
        U.u[0] = cvt2(lo.x, lo.y); U.u[1] = cvt2(lo.z, lo.w);
        U.u[2] = cvt2(hi.x, hi.y); U.u[3] = cvt2(hi.z, hi.w);
        a[m] = U.s;
      }
      #pragma unroll
      for (int n = 0; n < NR; ++n) {
        int row = n * 16 + lr, col = kk * 32 + lg * 8;
        b[n] = *(const short8*)&Bs[row * 64 + (col ^ ((row & 7) << 3))];
      }
      #pragma unroll
      for (int m = 0; m < MR; ++m)
        #pragma unroll
        for (int n = 0; n < NR; ++n)
          acc[m][n] = __builtin_amdgcn_mfma_f32_16x16x32_bf16(a[m], b[n], acc[m][n], 0, 0, 0);
    }
    if (kt + 1 < nk) {
      __syncthreads();
      dmaAf((kt + 1) * BK); dmaB((kt + 1) * BK);
      __syncthreads();
    }
  }

  #pragma unroll
  for (int m = 0; m < MR; ++m) {
    #pragma unroll
    for (int i = 0; i < 4; ++i) {
      long row = row0 + wave * WM + m * 16 + lg * 4 + i;
      float sq = 0.f;
      #pragma unroll
      for (int n = 0; n < NR; ++n) {
        long col = col0 + n * 16 + lr;
        float v = acc[m][n][i] + biasp[col];
        Cp[(size_t)row * 768 + col] = f2bs(v);
        sq += v * v;
      }
      #pragma unroll
      for (int off = 1; off < 16; off <<= 1) sq += __shfl_xor(sq, off);
      if (lr == 0) atomicAdd(&ssp[row], sq);
    }
  }
}

// all weight conversions in one dispatch
__global__ __launch_bounds__(256) void wconv_kernel(
    const float* __restrict__ Wx, const float* __restrict__ Wy,
    const float* __restrict__ ipw, const float* __restrict__ Wo,
    unsigned short* __restrict__ dWx, unsigned short* __restrict__ dWy,
    unsigned short* __restrict__ dWq, unsigned short* __restrict__ dWkT,
    unsigned short* __restrict__ dWv, unsigned short* __restrict__ dWo)
{
  long i = (long)blockIdx.x * 256 + threadIdx.x;
  if (i < 1179648) { dWx[i] = f2bs(Wx[i]); return; }
  i -= 1179648;
  if (i < 786432) { dWy[i] = f2bs(Wy[i]); return; }
  i -= 786432;
  if (i < 589824) { dWq[i] = f2bs(ipw[i]); return; }
  i -= 589824;
  if (i < 589824) {  // WkT[h][n][j] = Wk[h*64+j][n]
    int h = (int)(i / 49152), r = (int)(i % 49152);
    int nn = r >> 6, j = r & 63;
    dWkT[i] = f2bs(ipw[(size_t)(768 + h * 64 + j) * 768 + nn]);
    return;
  }
  i -= 589824;
  if (i < 589824) { dWv[i] = f2bs(ipw[2 * 589824 + i]); return; }
  i -= 589824;
  if (i < 589824) { dWo[i] = f2bs(Wo[i]); }
}

// Per-token fused: S = (qk . z)*invn -> softmax_w -> a = attn*invn -> u = a @ z
__global__ __launch_bounds__(256) void attn_kernel(
    const unsigned short* __restrict__ z, const unsigned short* __restrict__ qk,
    const float* __restrict__ ssy, unsigned short* __restrict__ u)
{
  __shared__ __align__(16) unsigned short zl[16 * 768];
  __shared__ __align__(16) unsigned short ql[12 * 768];
  __shared__ float sc[3][256];
  __shared__ float al[256];
  __shared__ float il[16];
  const int t = threadIdx.x;
  const long m = blockIdx.x;
  const int wv = t >> 6, lane = t & 63;
  const int lr = lane & 15, lg = lane >> 4;

  for (int s = t; s < 1536; s += 256) {
    int row = s / 96, g = s % 96;
    *(short8*)&zl[row * 768 + ((g ^ (row & 7)) << 3)] =
        *(const short8*)(z + m * 12288 + (size_t)s * 8);
  }
  for (int s = t; s < 1152; s += 256) {
    int row = s / 96, g = s % 96;
    *(short8*)&ql[row * 768 + ((g ^ (row & 7)) << 3)] =
        *(const short8*)(qk + m * 9216 + (size_t)s * 8);
  }
  if (t < 16) il[t] = 1.f / (sqrtf(ssy[m * 16 + t]) + 1e-6f);
  __syncthreads();

  f32x4 c = {0.f, 0.f, 0.f, 0.f};
  #pragma unroll
  for (int i = 0; i < 6; ++i) {
    int gb = wv * 24 + i * 4 + lg;
    short8 a = (lr < 12) ? *(const short8*)&ql[lr * 768 + ((gb ^ (lr & 7)) << 3)]
                         : short8{0, 0, 0, 0, 0, 0, 0, 0};
    short8 b = *(const short8*)&zl[lr * 768 + ((gb ^ (lr & 7)) << 3)];
    c = __builtin_amdgcn_mfma_f32_16x16x32_bf16(a, b, c, 0, 0, 0);
  }
  if (wv > 0) {
    #pragma unroll
    for (int i = 0; i < 4; ++i) sc[wv - 1][(lg * 4 + i) * 16 + lr] = c[i];
  }
  __syncthreads();
  if (wv == 0) {
    #pragma unroll
    for (int i = 0; i < 4; ++i) {
      int idx = (lg * 4 + i) * 16 + lr;
      float s = (c[i] + sc[0][idx] + sc[1][idx] + sc[2][idx]) * il[lr];
      float mx = s;
      #pragma unroll
      for (int off = 1; off < 16; off <<= 1) mx = fmaxf(mx, __shfl_xor(mx, off));
      float e = __expf(s - mx);
      float sum = e;
      #pragma unroll
      for (int off = 1; off < 16; off <<= 1) sum += __shfl_xor(sum, off);
      al[idx] = e / sum * il[lr];
    }
  }
  __syncthreads();

  for (int s = t; s < 1152; s += 256) {
    int h = s / 96, gd = s % 96;
    float acc[8] = {0.f, 0.f, 0.f, 0.f, 0.f, 0.f, 0.f, 0.f};
    #pragma unroll
    for (int w = 0; w < 16; ++w) {
      float aw = al[h * 16 + w];
      short8 zz = *(const short8*)&zl[w * 768 + ((gd ^ (w & 7)) << 3)];
      #pragma unroll
      for (int j = 0; j < 8; ++j) acc[j] += aw * b2f((unsigned short)zz[j]);
    }
    short8 o;
    #pragma unroll
    for (int j = 0; j < 8; ++j) o[j] = (short)f2bs(acc[j]);
    *(short8*)&u[m * 9216 + (size_t)s * 8] = o;
  }
}

__global__ __launch_bounds__(256) void ln_kernel(const float* __restrict__ R,
                                                 const float* __restrict__ w,
                                                 const float* __restrict__ b,
                                                 float* __restrict__ out) {
  const long row = blockIdx.x;
  const int t = threadIdx.x;
  const float* rr = R + row * 768;
  float v0 = rr[t], v1 = rr[t + 256], v2 = rr[t + 512];
  float s = v0 + v1 + v2;
  #pragma unroll
  for (int off = 1; off < 64; off <<= 1) s += __shfl_xor(s, off);
  __shared__ float ps[4];
  __shared__ float ps2[4];
  const int wave = t >> 6, lane = t & 63;
  if (lane == 0) ps[wave] = s;
  __syncthreads();
  const float mean = (ps[0] + ps[1] + ps[2] + ps[3]) * (1.f / 768.f);
  const float d0 = v0 - mean, d1 = v1 - mean, d2 = v2 - mean;
  float q = d0 * d0 + d1 * d1 + d2 * d2;
  #pragma unroll
  for (int off = 1; off < 64; off <<= 1) q += __shfl_xor(q, off);
  if (lane == 0) ps2[wave] = q;
  __syncthreads();
  const float var = (ps2[0] + ps2[1] + ps2[2] + ps2[3]) * (1.f / 768.f);
  const float rs = rsqrtf(var + 1e-6f);
  float* oo = out + row * 768;
  oo[t]       = d0 * rs * w[t]       + b[t];
  oo[t + 256] = d1 * rs * w[t + 256] + b[t + 256];
  oo[t + 512] = d2 * rs * w[t + 512] + b[t + 512];
}

extern "C" void kernel_launch(void* const* d_in, const int* in_sizes, int n_in,
                              void* d_out, int out_size, void* d_ws, size_t ws_size,
                              hipStream_t stream) {
  const float* x   = (const float*)d_in[0];   // (8,1024,1536)
  const float* y   = (const float*)d_in[1];   // (8,16384,1024)
  const float* Wx  = (const float*)d_in[2];   // (768,1536)
  const float* bx  = (const float*)d_in[3];
  const float* Wy  = (const float*)d_in[4];   // (768,1024)
  const float* by  = (const float*)d_in[5];
  const float* ipw = (const float*)d_in[6];   // (2304,768)
  const float* ipb = (const float*)d_in[7];
  const float* Wo  = (const float*)d_in[8];   // (768,768)
  const float* ob  = (const float*)d_in[9];
  const float* lnw = (const float*)d_in[10];
  const float* lnb = (const float*)d_in[11];
  float* out = (float*)d_out;

  char* ws = (char*)d_ws;
  size_t off = 0;
  auto alloc = [&](size_t bytes) {
    void* p = ws + off;
    off += (bytes + 4095) & ~(size_t)4095;
    return p;
  };
  unsigned short* Wx_b  = (unsigned short*)alloc(768L * 1536 * 2);
  unsigned short* Wy_b  = (unsigned short*)alloc(768L * 1024 * 2);
  unsigned short* Wq_b  = (unsigned short*)alloc(768L * 768 * 2);
  unsigned short* WkT_b = (unsigned short*)alloc(768L * 768 * 2);
  unsigned short* Wv_b  = (unsigned short*)alloc(768L * 768 * 2);
  unsigned short* Wo_b  = (unsigned short*)alloc(768L * 768 * 2);
  float* ssx = (float*)alloc(8192L * 4);
  float* ssy = (float*)alloc(131072L * 4);
  unsigned short* z_b  = (unsigned short*)alloc(131072L * 768 * 2);
  unsigned short* xq_b = (unsigned short*)alloc(8192L * 768 * 2);
  char* reg = (char*)alloc(134217728L * 2);    // 256 MB scratch region
  unsigned short* q_b  = (unsigned short*)(reg + 25165824);       // 12.6 MB
  unsigned short* qk_b = (unsigned short*)(reg + 37748736);       // 151 MB (also u)
  unsigned short* o_b  = (unsigned short*)(reg + 188743680);      // 12.6 MB
  float*          r_f  = (float*)(reg + 201326592);               // 25.2 MB
  (void)ws_size; (void)in_sizes; (void)n_in; (void)out_size;

  hipMemsetAsync(ssx, 0, 8192L * 4, stream);
  hipMemsetAsync(ssy, 0, 131072L * 4, stream);

  // all weights -> bf16 in one dispatch (4325376 elems)
  wconv_kernel<<<16896, 256, 0, stream>>>(Wx, Wy, ipw, Wo,
                                          Wx_b, Wy_b, Wq_b, WkT_b, Wv_b, Wo_b);

  // merged dispatch: blocks [0,6144) z = y@Wy^T+by (XCD1D);
  //                  blocks [6144,6528) xq_raw = x@Wx^T+bx. Both + row sumsq.
  gemm_af32_dual<<<6528, 256, 0, stream>>>(
      y, (const short*)Wy_b, z_b, by, ssy, 1024, 6, 6144,
      x, (const short*)Wx_b, xq_b, bx, ssx, 1536);

  // q = rs[m]*(xq_raw @ Wq^T) + bq   (rowscale folded into epilogue), BM=64
  gemm_bt<64, 128, EPI_BF16, false><<<dim3(128, 6, 1), 256, 0, stream>>>(
      (const short*)xq_b, (const short*)Wq_b, q_b, ipb, nullptr, nullptr, ssx,
      768, 768, 768, 768, 1.f, 0, 0, 0, 0, 0);

  // qk[m,h,:] = scale * q[m,h*64:+64] @ WkT[h]   (bk dropped: softmax-invariant)
  gemm_bt<128, 128, EPI_BF16, false><<<dim3(64, 6, 12), 256, 0, stream>>>(
      (const short*)q_b, (const short*)WkT_b, qk_b, nullptr, nullptr, nullptr, nullptr,
      768, 64, 9216, 64, 0.125f, 64, 49152, 768, 0, 0);

  // fused scores/softmax/u  (u overwrites qk slice per token)
  attn_kernel<<<8192, 256, 0, stream>>>(z_b, qk_b, ssy, qk_b);

  // o[:,h*64:+64] = u[:,h,:] @ Wv_h^T + bv_h
  gemm_bt<128, 64, EPI_BF16, false><<<dim3(64, 1, 12), 256, 0, stream>>>(
      (const short*)qk_b, (const short*)Wv_b, o_b, ipb + 1536, nullptr, nullptr, nullptr,
      9216, 768, 768, 768, 1.f, 768, 49152, 64, 64, 0);

  // r = o @ out_w^T + out_b + rs[m]*xq_raw   (residual row-scale), BM=64
  gemm_bt<64, 128, EPI_F32_RESID, false><<<dim3(128, 6, 1), 256, 0, stream>>>(
      (const short*)o_b, (const short*)Wo_b, r_f, ob, xq_b, nullptr, ssx,
      768, 768, 768, 768, 1.f, 0, 0, 0, 0, 0);

  ln_kernel<<<8192, 256, 0, stream>>>(r_f, lnw, lnb, out);
}